// Round 1
// baseline (777.469 us; speedup 1.0000x reference)
//
#include <hip/hip_runtime.h>
#include <math.h>

#define HDIM 128
#define BN 32

// ---------- CSR build ----------
__global__ void k_zero(int* cnt, int n){
  int i = blockIdx.x*256 + threadIdx.x;
  if (i<n) cnt[i]=0;
}

__global__ void k_count(const int* __restrict__ dst, int* __restrict__ cnt, int e){
  int i = blockIdx.x*256 + threadIdx.x;
  if (i<e) atomicAdd(&cnt[dst[i]], 1);
}

__global__ void k_dis(const int* __restrict__ cnt, float* __restrict__ dis, int n){
  int i = blockIdx.x*256 + threadIdx.x;
  if (i<n) dis[i] = rsqrtf((float)(cnt[i]+1));  // +1 self-loop; deg >= 1 always
}

__global__ void k_scan1(const int* __restrict__ cnt, int* __restrict__ off, int* __restrict__ bsum, int n){
  __shared__ int tmp[256];
  int t = threadIdx.x; int i = blockIdx.x*256 + t;
  int v = (i<n) ? cnt[i] : 0;
  tmp[t] = v; __syncthreads();
  for (int d=1; d<256; d<<=1){
    int a = (t>=d) ? tmp[t-d] : 0;
    __syncthreads(); tmp[t] += a; __syncthreads();
  }
  if (i<n) off[i] = tmp[t] - v;           // exclusive within block
  if (t==255) bsum[blockIdx.x] = tmp[255];
}

// single block; assumes nblocks <= 512 (N<=131072 -> 391 blocks here)
__global__ void k_scan2(const int* __restrict__ bsum, int* __restrict__ bpre, int nb){
  __shared__ int tmp[512];
  int t = threadIdx.x;
  int v = (t<nb) ? bsum[t] : 0;
  tmp[t] = v; __syncthreads();
  for (int d=1; d<512; d<<=1){
    int a = (t>=d) ? tmp[t-d] : 0;
    __syncthreads(); tmp[t] += a; __syncthreads();
  }
  if (t<nb) bpre[t] = tmp[t] - v;
}

__global__ void k_scan3(int* __restrict__ off, int* __restrict__ cur, const int* __restrict__ bpre, int n){
  int i = blockIdx.x*256 + threadIdx.x;
  if (i<n){ int o = off[i] + bpre[blockIdx.x]; off[i]=o; cur[i]=o; }
}

// bucket edges by dst; store (src, norm) interleaved as one 8B record
__global__ void k_scatter(const int* __restrict__ src, const int* __restrict__ dst,
                          const float* __restrict__ dis, int* __restrict__ cur,
                          int2* __restrict__ cw, int e){
  int i = blockIdx.x*256 + threadIdx.x;
  if (i>=e) return;
  int s = src[i], d = dst[i];
  int pos = atomicAdd(&cur[d], 1);
  int2 v; v.x = s; v.y = __float_as_int(dis[s]*dis[d]);
  cw[pos] = v;
}

// ---------- scalar aggregation: s = A_norm * x ----------
__global__ void k_sagg(const float* __restrict__ x, const int* __restrict__ off, const int* __restrict__ cnt,
                       const int2* __restrict__ cw, const float* __restrict__ dis,
                       float* __restrict__ s, int n){
  int i = blockIdx.x*256 + threadIdx.x;
  if (i>=n) return;
  int b = off[i], e = b + cnt[i];
  float di = dis[i];
  float acc = di*di*x[i];
  for (int k=b;k<e;k++){
    int2 v = cw[k];
    acc = fmaf(__int_as_float(v.y), x[v.x], acc);
  }
  s[i] = acc;
}

// h0[i][c] = relu(s[i]*W0[c] + b0[c]); one float4 per thread
__global__ void k_h0(const float* __restrict__ s, const float* __restrict__ W0, const float* __restrict__ b0,
                     float* __restrict__ h, int n){
  int idx = blockIdx.x*256 + threadIdx.x;
  int i = idx>>5, c4 = idx&31;
  if (i>=n) return;
  float sv = s[i];
  float4 w = ((const float4*)W0)[c4];
  float4 b = ((const float4*)b0)[c4];
  float4 o;
  o.x = fmaxf(fmaf(sv,w.x,b.x),0.f);
  o.y = fmaxf(fmaf(sv,w.y,b.y),0.f);
  o.z = fmaxf(fmaf(sv,w.z,b.z),0.f);
  o.w = fmaxf(fmaf(sv,w.w,b.w),0.f);
  ((float4*)(h + (size_t)i*HDIM))[c4] = o;
}

// ---------- wide aggregation: g = A_norm * h ; one wave per node ----------
__global__ __launch_bounds__(256) void k_wagg(const float* __restrict__ h, const int* __restrict__ off,
                       const int* __restrict__ cnt, const int2* __restrict__ cw,
                       const float* __restrict__ dis, float* __restrict__ g, int n){
  int wave = threadIdx.x>>6, lane = threadIdx.x&63;
  int i = blockIdx.x*4 + wave;
  if (i>=n) return;
  int b = off[i], e = b + cnt[i];
  float di = dis[i];
  float2 sv = ((const float2*)(h + (size_t)i*HDIM))[lane];
  float w2 = di*di;
  float2 acc; acc.x = w2*sv.x; acc.y = w2*sv.y;
  for (int k=b;k<e;k++){
    int2 v = cw[k];
    float w = __int_as_float(v.y);
    float2 hv = ((const float2*)(h + (size_t)v.x*HDIM))[lane];
    acc.x = fmaf(w,hv.x,acc.x); acc.y = fmaf(w,hv.y,acc.y);
  }
  ((float2*)(g + (size_t)i*HDIM))[lane] = acc;
}

// ---------- dense: h' = relu(g @ W + b), fp32 vector ----------
__global__ __launch_bounds__(256) void k_mm(const float* __restrict__ g, const float* __restrict__ W,
                     const float* __restrict__ b, float* __restrict__ h, int n){
  __shared__ float Ws[HDIM*HDIM];   // 64KB
  __shared__ float gs[BN*HDIM];     // 16KB
  int t = threadIdx.x;
  const float4* W4 = (const float4*)W;
  float4* Ws4 = (float4*)Ws;
  #pragma unroll
  for (int i=0;i<16;i++) Ws4[t + i*256] = W4[t + i*256];
  int n0 = blockIdx.x*BN;
  const float4* g4 = (const float4*)(g + (size_t)n0*HDIM);
  float4* gs4 = (float4*)gs;
  for (int i=t;i<BN*32;i+=256){
    int row = i>>5;
    gs4[i] = (n0+row<n) ? g4[i] : make_float4(0.f,0.f,0.f,0.f);
  }
  __syncthreads();
  int nl = t>>3, cg = t&7;            // node-local 0..31, channel group 0..7 (16 ch)
  float acc[16];
  #pragma unroll
  for (int j=0;j<16;j++) acc[j]=0.f;
  const float* gr = gs + nl*HDIM;
  for (int k=0;k<HDIM;k++){
    float gv = gr[k];
    const float4* wr = (const float4*)(Ws + (k<<7)) + (cg<<2);
    float4 a0=wr[0], a1=wr[1], a2=wr[2], a3=wr[3];
    acc[0]=fmaf(gv,a0.x,acc[0]);  acc[1]=fmaf(gv,a0.y,acc[1]);
    acc[2]=fmaf(gv,a0.z,acc[2]);  acc[3]=fmaf(gv,a0.w,acc[3]);
    acc[4]=fmaf(gv,a1.x,acc[4]);  acc[5]=fmaf(gv,a1.y,acc[5]);
    acc[6]=fmaf(gv,a1.z,acc[6]);  acc[7]=fmaf(gv,a1.w,acc[7]);
    acc[8]=fmaf(gv,a2.x,acc[8]);  acc[9]=fmaf(gv,a2.y,acc[9]);
    acc[10]=fmaf(gv,a2.z,acc[10]); acc[11]=fmaf(gv,a2.w,acc[11]);
    acc[12]=fmaf(gv,a3.x,acc[12]); acc[13]=fmaf(gv,a3.y,acc[13]);
    acc[14]=fmaf(gv,a3.z,acc[14]); acc[15]=fmaf(gv,a3.w,acc[15]);
  }
  int node = n0 + nl;
  if (node < n){
    const float4* b4 = (const float4*)(b + (cg<<4));
    float4* o4 = (float4*)(h + (size_t)node*HDIM + (cg<<4));
    #pragma unroll
    for (int q=0;q<4;q++){
      float4 bb = b4[q];
      float4 o;
      o.x = fmaxf(acc[q*4+0]+bb.x,0.f);
      o.y = fmaxf(acc[q*4+1]+bb.y,0.f);
      o.z = fmaxf(acc[q*4+2]+bb.z,0.f);
      o.w = fmaxf(acc[q*4+3]+bb.w,0.f);
      o4[q] = o;
    }
  }
}

// ---------- z[i] = h2[i] . Wo ; one wave per node, shuffle reduce ----------
__global__ __launch_bounds__(256) void k_z(const float* __restrict__ h, const float* __restrict__ Wo,
                    float* __restrict__ z, int n){
  int wave = threadIdx.x>>6, lane = threadIdx.x&63;
  int i = blockIdx.x*4 + wave;
  if (i>=n) return;
  float2 hv = ((const float2*)(h + (size_t)i*HDIM))[lane];
  float2 wv = ((const float2*)Wo)[lane];
  float v = hv.x*wv.x + hv.y*wv.y;
  #pragma unroll
  for (int o=32;o>0;o>>=1) v += __shfl_xor(v,o);
  if (lane==0) z[i]=v;
}

// ---------- y[i] = sigmoid(A_norm z + bo) ----------
__global__ void k_final(const float* __restrict__ z, const int* __restrict__ off, const int* __restrict__ cnt,
                        const int2* __restrict__ cw, const float* __restrict__ dis,
                        const float* __restrict__ bo, float* __restrict__ y, int n){
  int i = blockIdx.x*256 + threadIdx.x;
  if (i>=n) return;
  int b = off[i], e = b + cnt[i];
  float di = dis[i];
  float acc = di*di*z[i];
  for (int k=b;k<e;k++){
    int2 v = cw[k];
    acc = fmaf(__int_as_float(v.y), z[v.x], acc);
  }
  acc += bo[0];
  y[i] = 1.f/(1.f + expf(-acc));
}

extern "C" void kernel_launch(void* const* d_in, const int* in_sizes, int n_in,
                              void* d_out, int out_size, void* d_ws, size_t ws_size,
                              hipStream_t stream){
  const float* x  = (const float*)d_in[0];
  const int*   ei = (const int*)d_in[1];
  const float* W0 = (const float*)d_in[2];
  const float* b0 = (const float*)d_in[3];
  const float* W1 = (const float*)d_in[4];
  const float* b1 = (const float*)d_in[5];
  const float* W2 = (const float*)d_in[6];
  const float* b2 = (const float*)d_in[7];
  const float* Wo = (const float*)d_in[8];
  const float* bo = (const float*)d_in[9];
  int n = in_sizes[0];        // x is [N,1]
  int e = in_sizes[1]/2;      // edge_index is [2,E]
  const int* src = ei;
  const int* dst = ei + e;
  float* y = (float*)d_out;

  char* p = (char*)d_ws;
  auto alloc = [&](size_t bytes)->void*{ void* r=p; p += (bytes+255)&~(size_t)255; return r; };
  int*   cnt  = (int*)  alloc((size_t)n*4);
  int*   off  = (int*)  alloc((size_t)n*4);
  int*   cur  = (int*)  alloc((size_t)n*4);
  int*   bsum = (int*)  alloc(512*4);
  int*   bpre = (int*)  alloc(512*4);
  float* dis  = (float*)alloc((size_t)n*4);
  float* sb   = (float*)alloc((size_t)n*4);
  float* zb   = (float*)alloc((size_t)n*4);
  int2*  cw   = (int2*) alloc((size_t)e*8);
  float* hA   = (float*)alloc((size_t)n*HDIM*4);
  float* hB   = (float*)alloc((size_t)n*HDIM*4);

  int nb = (n+255)/256;
  int eb = (e+255)/256;

  k_zero   <<<nb,256,0,stream>>>(cnt,n);
  k_count  <<<eb,256,0,stream>>>(dst,cnt,e);
  k_dis    <<<nb,256,0,stream>>>(cnt,dis,n);
  k_scan1  <<<nb,256,0,stream>>>(cnt,off,bsum,n);
  k_scan2  <<<1,512,0,stream>>>(bsum,bpre,nb);
  k_scan3  <<<nb,256,0,stream>>>(off,cur,bpre,n);
  k_scatter<<<eb,256,0,stream>>>(src,dst,dis,cur,cw,e);

  k_sagg <<<nb,256,0,stream>>>(x,off,cnt,cw,dis,sb,n);
  k_h0   <<<(n*32+255)/256,256,0,stream>>>(sb,W0,b0,hA,n);

  k_wagg <<<(n+3)/4,256,0,stream>>>(hA,off,cnt,cw,dis,hB,n);
  k_mm   <<<(n+BN-1)/BN,256,0,stream>>>(hB,W1,b1,hA,n);

  k_wagg <<<(n+3)/4,256,0,stream>>>(hA,off,cnt,cw,dis,hB,n);
  k_mm   <<<(n+BN-1)/BN,256,0,stream>>>(hB,W2,b2,hA,n);

  k_z    <<<(n+3)/4,256,0,stream>>>(hA,Wo,zb,n);
  k_final<<<nb,256,0,stream>>>(zb,off,cnt,cw,dis,bo,y,n);
}

// Round 2
// 583.727 us; speedup vs baseline: 1.3319x; 1.3319x over previous
//
#include <hip/hip_runtime.h>
#include <math.h>

#define HDIM 128
#define BN 32

typedef unsigned int uint;
typedef unsigned short ushort;

// bf16 helpers (bit-level; bf16->fp32 exact, fp32->bf16 RNE)
__device__ __forceinline__ float bflo(uint u){ return __uint_as_float(u<<16); }
__device__ __forceinline__ float bfhi(uint u){ return __uint_as_float(u&0xffff0000u); }
__device__ __forceinline__ ushort f2bf(float f){
  uint x = __float_as_uint(f);
  return (ushort)((x + 0x7fffu + ((x>>16)&1u)) >> 16);
}
__device__ __forceinline__ uint pack2bf(float a, float b){
  return (uint)f2bf(a) | ((uint)f2bf(b)<<16);
}

// ---------- CSR build ----------
__global__ void k_zero(int* cnt, int n){
  int i = blockIdx.x*256 + threadIdx.x;
  if (i<n) cnt[i]=0;
}

__global__ void k_count(const int* __restrict__ dst, int* __restrict__ cnt, int e){
  int i = blockIdx.x*256 + threadIdx.x;
  if (i<e) atomicAdd(&cnt[dst[i]], 1);
}

__global__ void k_dis(const int* __restrict__ cnt, float* __restrict__ dis, int n){
  int i = blockIdx.x*256 + threadIdx.x;
  if (i<n) dis[i] = rsqrtf((float)(cnt[i]+1));  // +1 self-loop
}

__global__ void k_scan1(const int* __restrict__ cnt, int* __restrict__ off, int* __restrict__ bsum, int n){
  __shared__ int tmp[256];
  int t = threadIdx.x; int i = blockIdx.x*256 + t;
  int v = (i<n) ? cnt[i] : 0;
  tmp[t] = v; __syncthreads();
  for (int d=1; d<256; d<<=1){
    int a = (t>=d) ? tmp[t-d] : 0;
    __syncthreads(); tmp[t] += a; __syncthreads();
  }
  if (i<n) off[i] = tmp[t] - v;
  if (t==255) bsum[blockIdx.x] = tmp[255];
}

__global__ void k_scan2(const int* __restrict__ bsum, int* __restrict__ bpre, int nb){
  __shared__ int tmp[512];
  int t = threadIdx.x;
  int v = (t<nb) ? bsum[t] : 0;
  tmp[t] = v; __syncthreads();
  for (int d=1; d<512; d<<=1){
    int a = (t>=d) ? tmp[t-d] : 0;
    __syncthreads(); tmp[t] += a; __syncthreads();
  }
  if (t<nb) bpre[t] = tmp[t] - v;
}

__global__ void k_scan3(int* __restrict__ off, int* __restrict__ cur, const int* __restrict__ bpre, int n){
  int i = blockIdx.x*256 + threadIdx.x;
  if (i<n){ int o = off[i] + bpre[blockIdx.x]; off[i]=o; cur[i]=o; }
}

__global__ void k_scatter(const int* __restrict__ src, const int* __restrict__ dst,
                          const float* __restrict__ dis, int* __restrict__ cur,
                          int2* __restrict__ cw, int e){
  int i = blockIdx.x*256 + threadIdx.x;
  if (i>=e) return;
  int s = src[i], d = dst[i];
  int pos = atomicAdd(&cur[d], 1);
  int2 v; v.x = s; v.y = __float_as_int(dis[s]*dis[d]);
  cw[pos] = v;
}

// ---------- scalar aggregation: s = A_norm * x ----------
__global__ void k_sagg(const float* __restrict__ x, const int* __restrict__ off, const int* __restrict__ cnt,
                       const int2* __restrict__ cw, const float* __restrict__ dis,
                       float* __restrict__ s, int n){
  int i = blockIdx.x*256 + threadIdx.x;
  if (i>=n) return;
  int b = off[i], e = b + cnt[i];
  float di = dis[i];
  float acc = di*di*x[i];
  for (int k=b;k<e;k++){
    int2 v = cw[k];
    acc = fmaf(__int_as_float(v.y), x[v.x], acc);
  }
  s[i] = acc;
}

// h0[i][c] = relu(s[i]*W0[c] + b0[c]) -> bf16 table
__global__ void k_h0(const float* __restrict__ s, const float* __restrict__ W0, const float* __restrict__ b0,
                     uint* __restrict__ h, int n){
  int idx = blockIdx.x*256 + threadIdx.x;
  int i = idx>>5, c4 = idx&31;
  if (i>=n) return;
  float sv = s[i];
  float4 w = ((const float4*)W0)[c4];
  float4 b = ((const float4*)b0)[c4];
  float o0 = fmaxf(fmaf(sv,w.x,b.x),0.f);
  float o1 = fmaxf(fmaf(sv,w.y,b.y),0.f);
  float o2 = fmaxf(fmaf(sv,w.z,b.z),0.f);
  float o3 = fmaxf(fmaf(sv,w.w,b.w),0.f);
  uint2 o; o.x = pack2bf(o0,o1); o.y = pack2bf(o2,o3);
  ((uint2*)(h + (size_t)i*64))[c4] = o;
}

// ---------- wide aggregation: g = A_norm * h(bf16) ; one wave per node ----------
// unroll-by-4: 4 independent gathers in flight per wave
__global__ __launch_bounds__(256) void k_wagg(const uint* __restrict__ h, const int* __restrict__ off,
                       const int* __restrict__ cnt, const int2* __restrict__ cw,
                       const float* __restrict__ dis, float* __restrict__ g, int n){
  int wave = threadIdx.x>>6, lane = threadIdx.x&63;
  int i = blockIdx.x*4 + wave;
  if (i>=n) return;
  int b = off[i], e = b + cnt[i];
  float di = dis[i];
  float w2 = di*di;
  uint su = h[(size_t)i*64 + lane];
  float2 acc; acc.x = w2*bflo(su); acc.y = w2*bfhi(su);
  int k = b;
  for (; k+4<=e; k+=4){
    int2 v0 = cw[k];   int2 v1 = cw[k+1];
    int2 v2 = cw[k+2]; int2 v3 = cw[k+3];
    uint u0 = h[(size_t)v0.x*64 + lane];
    uint u1 = h[(size_t)v1.x*64 + lane];
    uint u2 = h[(size_t)v2.x*64 + lane];
    uint u3 = h[(size_t)v3.x*64 + lane];
    float w0=__int_as_float(v0.y), w1c=__int_as_float(v1.y);
    float wc2=__int_as_float(v2.y), w3=__int_as_float(v3.y);
    acc.x = fmaf(w0, bflo(u0), acc.x); acc.y = fmaf(w0, bfhi(u0), acc.y);
    acc.x = fmaf(w1c,bflo(u1), acc.x); acc.y = fmaf(w1c,bfhi(u1), acc.y);
    acc.x = fmaf(wc2,bflo(u2), acc.x); acc.y = fmaf(wc2,bfhi(u2), acc.y);
    acc.x = fmaf(w3, bflo(u3), acc.x); acc.y = fmaf(w3, bfhi(u3), acc.y);
  }
  for (; k<e; ++k){
    int2 v = cw[k];
    uint u = h[(size_t)v.x*64 + lane];
    float w = __int_as_float(v.y);
    acc.x = fmaf(w, bflo(u), acc.x); acc.y = fmaf(w, bfhi(u), acc.y);
  }
  ((float2*)(g + (size_t)i*HDIM))[lane] = acc;
}

// ---------- dense: h' = relu(g @ W + b) fp32 compute, bf16 output table ----------
__global__ __launch_bounds__(256) void k_mm(const float* __restrict__ g, const float* __restrict__ W,
                     const float* __restrict__ b, uint* __restrict__ h, int n){
  __shared__ float Ws[HDIM*HDIM];   // 64KB
  __shared__ float gs[BN*HDIM];     // 16KB
  int t = threadIdx.x;
  const float4* W4 = (const float4*)W;
  float4* Ws4 = (float4*)Ws;
  #pragma unroll
  for (int i=0;i<16;i++) Ws4[t + i*256] = W4[t + i*256];
  int n0 = blockIdx.x*BN;
  const float4* g4 = (const float4*)(g + (size_t)n0*HDIM);
  float4* gs4 = (float4*)gs;
  for (int i=t;i<BN*32;i+=256){
    int row = i>>5;
    gs4[i] = (n0+row<n) ? g4[i] : make_float4(0.f,0.f,0.f,0.f);
  }
  __syncthreads();
  int nl = t>>3, cg = t&7;
  float acc[16];
  #pragma unroll
  for (int j=0;j<16;j++) acc[j]=0.f;
  const float* gr = gs + nl*HDIM;
  for (int k=0;k<HDIM;k++){
    float gv = gr[k];
    const float4* wr = (const float4*)(Ws + (k<<7)) + (cg<<2);
    float4 a0=wr[0], a1=wr[1], a2=wr[2], a3=wr[3];
    acc[0]=fmaf(gv,a0.x,acc[0]);  acc[1]=fmaf(gv,a0.y,acc[1]);
    acc[2]=fmaf(gv,a0.z,acc[2]);  acc[3]=fmaf(gv,a0.w,acc[3]);
    acc[4]=fmaf(gv,a1.x,acc[4]);  acc[5]=fmaf(gv,a1.y,acc[5]);
    acc[6]=fmaf(gv,a1.z,acc[6]);  acc[7]=fmaf(gv,a1.w,acc[7]);
    acc[8]=fmaf(gv,a2.x,acc[8]);  acc[9]=fmaf(gv,a2.y,acc[9]);
    acc[10]=fmaf(gv,a2.z,acc[10]); acc[11]=fmaf(gv,a2.w,acc[11]);
    acc[12]=fmaf(gv,a3.x,acc[12]); acc[13]=fmaf(gv,a3.y,acc[13]);
    acc[14]=fmaf(gv,a3.z,acc[14]); acc[15]=fmaf(gv,a3.w,acc[15]);
  }
  int node = n0 + nl;
  if (node < n){
    const float4* b4 = (const float4*)(b + (cg<<4));
    uint4 o[2];
    #pragma unroll
    for (int q=0;q<4;q++){
      float4 bb = b4[q];
      float r0 = fmaxf(acc[q*4+0]+bb.x,0.f);
      float r1 = fmaxf(acc[q*4+1]+bb.y,0.f);
      float r2 = fmaxf(acc[q*4+2]+bb.z,0.f);
      float r3 = fmaxf(acc[q*4+3]+bb.w,0.f);
      ((uint*)o)[q*2+0] = pack2bf(r0,r1);
      ((uint*)o)[q*2+1] = pack2bf(r2,r3);
    }
    uint4* o4 = (uint4*)(h + (size_t)node*64 + (cg<<3));
    o4[0]=o[0]; o4[1]=o[1];
  }
}

// ---------- z[i] = h2(bf16)[i] . Wo ; one wave per node, shuffle reduce ----------
__global__ __launch_bounds__(256) void k_z(const uint* __restrict__ h, const float* __restrict__ Wo,
                    float* __restrict__ z, int n){
  int wave = threadIdx.x>>6, lane = threadIdx.x&63;
  int i = blockIdx.x*4 + wave;
  if (i>=n) return;
  uint u = h[(size_t)i*64 + lane];
  float2 wv = ((const float2*)Wo)[lane];
  float v = bflo(u)*wv.x + bfhi(u)*wv.y;
  #pragma unroll
  for (int o=32;o>0;o>>=1) v += __shfl_xor(v,o);
  if (lane==0) z[i]=v;
}

// ---------- y[i] = sigmoid(A_norm z + bo) ----------
__global__ void k_final(const float* __restrict__ z, const int* __restrict__ off, const int* __restrict__ cnt,
                        const int2* __restrict__ cw, const float* __restrict__ dis,
                        const float* __restrict__ bo, float* __restrict__ y, int n){
  int i = blockIdx.x*256 + threadIdx.x;
  if (i>=n) return;
  int b = off[i], e = b + cnt[i];
  float di = dis[i];
  float acc = di*di*z[i];
  for (int k=b;k<e;k++){
    int2 v = cw[k];
    acc = fmaf(__int_as_float(v.y), z[v.x], acc);
  }
  acc += bo[0];
  y[i] = 1.f/(1.f + expf(-acc));
}

extern "C" void kernel_launch(void* const* d_in, const int* in_sizes, int n_in,
                              void* d_out, int out_size, void* d_ws, size_t ws_size,
                              hipStream_t stream){
  const float* x  = (const float*)d_in[0];
  const int*   ei = (const int*)d_in[1];
  const float* W0 = (const float*)d_in[2];
  const float* b0 = (const float*)d_in[3];
  const float* W1 = (const float*)d_in[4];
  const float* b1 = (const float*)d_in[5];
  const float* W2 = (const float*)d_in[6];
  const float* b2 = (const float*)d_in[7];
  const float* Wo = (const float*)d_in[8];
  const float* bo = (const float*)d_in[9];
  int n = in_sizes[0];
  int e = in_sizes[1]/2;
  const int* src = ei;
  const int* dst = ei + e;
  float* y = (float*)d_out;

  char* p = (char*)d_ws;
  auto alloc = [&](size_t bytes)->void*{ void* r=p; p += (bytes+255)&~(size_t)255; return r; };
  int*   cnt  = (int*)  alloc((size_t)n*4);
  int*   off  = (int*)  alloc((size_t)n*4);
  int*   cur  = (int*)  alloc((size_t)n*4);
  int*   bsum = (int*)  alloc(512*4);
  int*   bpre = (int*)  alloc(512*4);
  float* dis  = (float*)alloc((size_t)n*4);
  float* sb   = (float*)alloc((size_t)n*4);
  float* zb   = (float*)alloc((size_t)n*4);
  int2*  cw   = (int2*) alloc((size_t)e*8);
  uint*  hb0  = (uint*) alloc((size_t)n*64*4);   // bf16 h tables (n x 128 x 2B = n*64 uints)
  uint*  hb1  = (uint*) alloc((size_t)n*64*4);
  float* gbuf = (float*)alloc((size_t)n*HDIM*4); // fp32 aggregated features

  int nb = (n+255)/256;
  int eb = (e+255)/256;

  k_zero   <<<nb,256,0,stream>>>(cnt,n);
  k_count  <<<eb,256,0,stream>>>(dst,cnt,e);
  k_dis    <<<nb,256,0,stream>>>(cnt,dis,n);
  k_scan1  <<<nb,256,0,stream>>>(cnt,off,bsum,n);
  k_scan2  <<<1,512,0,stream>>>(bsum,bpre,nb);
  k_scan3  <<<nb,256,0,stream>>>(off,cur,bpre,n);
  k_scatter<<<eb,256,0,stream>>>(src,dst,dis,cur,cw,e);

  k_sagg <<<nb,256,0,stream>>>(x,off,cnt,cw,dis,sb,n);
  k_h0   <<<(n*32+255)/256,256,0,stream>>>(sb,W0,b0,hb0,n);

  k_wagg <<<(n+3)/4,256,0,stream>>>(hb0,off,cnt,cw,dis,gbuf,n);
  k_mm   <<<(n+BN-1)/BN,256,0,stream>>>(gbuf,W1,b1,hb1,n);

  k_wagg <<<(n+3)/4,256,0,stream>>>(hb1,off,cnt,cw,dis,gbuf,n);
  k_mm   <<<(n+BN-1)/BN,256,0,stream>>>(gbuf,W2,b2,hb0,n);

  k_z    <<<(n+3)/4,256,0,stream>>>(hb0,Wo,zb,n);
  k_final<<<nb,256,0,stream>>>(zb,off,cnt,cw,dis,bo,y,n);
}

// Round 3
// 399.579 us; speedup vs baseline: 1.9457x; 1.4609x over previous
//
#include <hip/hip_runtime.h>
#include <math.h>

#define HDIM 128
#define BN 32

typedef unsigned int uint;
typedef unsigned short ushort;
typedef __attribute__((ext_vector_type(8))) short short8;
typedef __attribute__((ext_vector_type(4))) float f32x4;

// bf16 helpers (bit-level; bf16->fp32 exact, fp32->bf16 RNE)
__device__ __forceinline__ float bflo(uint u){ return __uint_as_float(u<<16); }
__device__ __forceinline__ float bfhi(uint u){ return __uint_as_float(u&0xffff0000u); }
__device__ __forceinline__ ushort f2bf(float f){
  uint x = __float_as_uint(f);
  return (ushort)((x + 0x7fffu + ((x>>16)&1u)) >> 16);
}
__device__ __forceinline__ uint pack2bf(float a, float b){
  return (uint)f2bf(a) | ((uint)f2bf(b)<<16);
}

// ---------- CSR build ----------
__global__ void k_zero(int* cnt, int n){
  int i = blockIdx.x*256 + threadIdx.x;
  if (i<n) cnt[i]=0;
}

__global__ void k_count(const int* __restrict__ dst, int* __restrict__ cnt, int e){
  int i = blockIdx.x*256 + threadIdx.x;
  if (i<e) atomicAdd(&cnt[dst[i]], 1);
}

__global__ void k_dis(const int* __restrict__ cnt, float* __restrict__ dis, int n){
  int i = blockIdx.x*256 + threadIdx.x;
  if (i<n) dis[i] = rsqrtf((float)(cnt[i]+1));  // +1 self-loop
}

__global__ void k_scan1(const int* __restrict__ cnt, int* __restrict__ off, int* __restrict__ bsum, int n){
  __shared__ int tmp[256];
  int t = threadIdx.x; int i = blockIdx.x*256 + t;
  int v = (i<n) ? cnt[i] : 0;
  tmp[t] = v; __syncthreads();
  for (int d=1; d<256; d<<=1){
    int a = (t>=d) ? tmp[t-d] : 0;
    __syncthreads(); tmp[t] += a; __syncthreads();
  }
  if (i<n) off[i] = tmp[t] - v;
  if (t==255) bsum[blockIdx.x] = tmp[255];
}

__global__ void k_scan2(const int* __restrict__ bsum, int* __restrict__ bpre, int nb){
  __shared__ int tmp[512];
  int t = threadIdx.x;
  int v = (t<nb) ? bsum[t] : 0;
  tmp[t] = v; __syncthreads();
  for (int d=1; d<512; d<<=1){
    int a = (t>=d) ? tmp[t-d] : 0;
    __syncthreads(); tmp[t] += a; __syncthreads();
  }
  if (t<nb) bpre[t] = tmp[t] - v;
}

__global__ void k_scan3(int* __restrict__ off, int* __restrict__ cur, const int* __restrict__ bpre, int n){
  int i = blockIdx.x*256 + threadIdx.x;
  if (i<n){ int o = off[i] + bpre[blockIdx.x]; off[i]=o; cur[i]=o; }
}

__global__ void k_scatter(const int* __restrict__ src, const int* __restrict__ dst,
                          const float* __restrict__ dis, int* __restrict__ cur,
                          int2* __restrict__ cw, int e){
  int i = blockIdx.x*256 + threadIdx.x;
  if (i>=e) return;
  int s = src[i], d = dst[i];
  int pos = atomicAdd(&cur[d], 1);
  int2 v; v.x = s; v.y = __float_as_int(dis[s]*dis[d]);
  cw[pos] = v;
}

// ---------- W transpose + bf16: Wt[out][in] ----------
__global__ void k_wt(const float* __restrict__ W, ushort* __restrict__ Wt){
  int idx = blockIdx.x*256 + threadIdx.x;   // 16384 total
  int no = idx>>7, k = idx&127;
  Wt[idx] = f2bf(W[k*HDIM + no]);
}

// ---------- scalar aggregation: s = A_norm * x ----------
__global__ void k_sagg(const float* __restrict__ x, const int* __restrict__ off, const int* __restrict__ cnt,
                       const int2* __restrict__ cw, const float* __restrict__ dis,
                       float* __restrict__ s, int n){
  int i = blockIdx.x*256 + threadIdx.x;
  if (i>=n) return;
  int b = off[i], e = b + cnt[i];
  float di = dis[i];
  float acc = di*di*x[i];
  for (int k=b;k<e;k++){
    int2 v = cw[k];
    acc = fmaf(__int_as_float(v.y), x[v.x], acc);
  }
  s[i] = acc;
}

// h0[i][c] = relu(s[i]*W0[c] + b0[c]) -> bf16 table
__global__ void k_h0(const float* __restrict__ s, const float* __restrict__ W0, const float* __restrict__ b0,
                     uint* __restrict__ h, int n){
  int idx = blockIdx.x*256 + threadIdx.x;
  int i = idx>>5, c4 = idx&31;
  if (i>=n) return;
  float sv = s[i];
  float4 w = ((const float4*)W0)[c4];
  float4 b = ((const float4*)b0)[c4];
  float o0 = fmaxf(fmaf(sv,w.x,b.x),0.f);
  float o1 = fmaxf(fmaf(sv,w.y,b.y),0.f);
  float o2 = fmaxf(fmaf(sv,w.z,b.z),0.f);
  float o3 = fmaxf(fmaf(sv,w.w,b.w),0.f);
  uint2 o; o.x = pack2bf(o0,o1); o.y = pack2bf(o2,o3);
  ((uint2*)(h + (size_t)i*64))[c4] = o;
}

// ---------- wide aggregation: g(bf16) = A_norm * h(bf16) ; one wave per node ----------
__global__ __launch_bounds__(256) void k_wagg(const uint* __restrict__ h, const int* __restrict__ off,
                       const int* __restrict__ cnt, const int2* __restrict__ cw,
                       const float* __restrict__ dis, uint* __restrict__ g, int n){
  int wave = threadIdx.x>>6, lane = threadIdx.x&63;
  int i = blockIdx.x*4 + wave;
  if (i>=n) return;
  int b = off[i], e = b + cnt[i];
  float di = dis[i];
  float w2 = di*di;
  uint su = h[(size_t)i*64 + lane];
  float2 acc; acc.x = w2*bflo(su); acc.y = w2*bfhi(su);
  int k = b;
  for (; k+4<=e; k+=4){
    int2 v0 = cw[k];   int2 v1 = cw[k+1];
    int2 v2 = cw[k+2]; int2 v3 = cw[k+3];
    uint u0 = h[(size_t)v0.x*64 + lane];
    uint u1 = h[(size_t)v1.x*64 + lane];
    uint u2 = h[(size_t)v2.x*64 + lane];
    uint u3 = h[(size_t)v3.x*64 + lane];
    float w0=__int_as_float(v0.y), w1c=__int_as_float(v1.y);
    float wc2=__int_as_float(v2.y), w3=__int_as_float(v3.y);
    acc.x = fmaf(w0, bflo(u0), acc.x); acc.y = fmaf(w0, bfhi(u0), acc.y);
    acc.x = fmaf(w1c,bflo(u1), acc.x); acc.y = fmaf(w1c,bfhi(u1), acc.y);
    acc.x = fmaf(wc2,bflo(u2), acc.x); acc.y = fmaf(wc2,bfhi(u2), acc.y);
    acc.x = fmaf(w3, bflo(u3), acc.x); acc.y = fmaf(w3, bfhi(u3), acc.y);
  }
  for (; k<e; ++k){
    int2 v = cw[k];
    uint u = h[(size_t)v.x*64 + lane];
    float w = __int_as_float(v.y);
    acc.x = fmaf(w, bflo(u), acc.x); acc.y = fmaf(w, bfhi(u), acc.y);
  }
  g[(size_t)i*64 + lane] = pack2bf(acc.x, acc.y);
}

// ---------- dense via MFMA: h' = relu(g @ W + b), bf16 in/out ----------
// block = 256 thr = 4 waves; 64 rows/block; A frag k contiguous (m97-verified),
// C/D: col=l&15, row=(l>>4)*4+q (m89-verified). T2 16B-slot XOR swizzle in LDS.
__global__ __launch_bounds__(256) void k_mm(const uint* __restrict__ g, const ushort* __restrict__ Wt,
                     const float* __restrict__ b, ushort* __restrict__ h, int n){
  __shared__ uint4 Ws4[2048];   // Wt[128][128] bf16, swizzled, 32KB
  __shared__ uint4 As4[1024];   // g[64][128] bf16, swizzled, 16KB
  int t = threadIdx.x;
  int n0 = blockIdx.x*64;

  const uint4* Wg = (const uint4*)Wt;
  #pragma unroll
  for (int i=0;i<8;i++){
    int c = t + i*256;                 // chunk 0..2047
    int row = c>>4, slot = c&15;
    Ws4[row*16 + (slot^(row&7))] = Wg[c];
  }
  const uint4* Gg = (const uint4*)g;
  #pragma unroll
  for (int i=0;i<4;i++){
    int c = t + i*256;                 // chunk 0..1023
    int row = c>>4, slot = c&15;
    uint4 v = make_uint4(0,0,0,0);
    if (n0 + row < n) v = Gg[(size_t)(n0+row)*16 + slot];
    As4[row*16 + (slot^(row&7))] = v;
  }
  __syncthreads();

  int w = t>>6, l = t&63;
  int lr = l&15, lg = l>>4;            // frag row/col & k-group
  f32x4 acc[8];
  #pragma unroll
  for (int j=0;j<8;j++) acc[j] = (f32x4){0.f,0.f,0.f,0.f};

  float bv[8];
  #pragma unroll
  for (int j=0;j<8;j++) bv[j] = b[16*j + lr];

  #pragma unroll
  for (int s=0;s<4;s++){
    short8 a = *(const short8*)&As4[(16*w + lr)*16 + ((4*s + lg)^(lr&7))];
    #pragma unroll
    for (int j=0;j<8;j++){
      short8 bb = *(const short8*)&Ws4[(16*j + lr)*16 + ((4*s + lg)^(lr&7))];
      acc[j] = __builtin_amdgcn_mfma_f32_16x16x32_bf16(a, bb, acc[j], 0, 0, 0);
    }
  }

  #pragma unroll
  for (int j=0;j<8;j++){
    int col = 16*j + lr;
    #pragma unroll
    for (int q=0;q<4;q++){
      int node = n0 + 16*w + lg*4 + q;
      if (node < n){
        float v = fmaxf(acc[j][q] + bv[j], 0.f);
        h[(size_t)node*HDIM + col] = f2bf(v);
      }
    }
  }
}

// ---------- z[i] = h2(bf16)[i] . Wo ; one wave per node, shuffle reduce ----------
__global__ __launch_bounds__(256) void k_z(const uint* __restrict__ h, const float* __restrict__ Wo,
                    float* __restrict__ z, int n){
  int wave = threadIdx.x>>6, lane = threadIdx.x&63;
  int i = blockIdx.x*4 + wave;
  if (i>=n) return;
  uint u = h[(size_t)i*64 + lane];
  float2 wv = ((const float2*)Wo)[lane];
  float v = bflo(u)*wv.x + bfhi(u)*wv.y;
  #pragma unroll
  for (int o=32;o>0;o>>=1) v += __shfl_xor(v,o);
  if (lane==0) z[i]=v;
}

// ---------- y[i] = sigmoid(A_norm z + bo) ----------
__global__ void k_final(const float* __restrict__ z, const int* __restrict__ off, const int* __restrict__ cnt,
                        const int2* __restrict__ cw, const float* __restrict__ dis,
                        const float* __restrict__ bo, float* __restrict__ y, int n){
  int i = blockIdx.x*256 + threadIdx.x;
  if (i>=n) return;
  int b = off[i], e = b + cnt[i];
  float di = dis[i];
  float acc = di*di*z[i];
  for (int k=b;k<e;k++){
    int2 v = cw[k];
    acc = fmaf(__int_as_float(v.y), z[v.x], acc);
  }
  acc += bo[0];
  y[i] = 1.f/(1.f + expf(-acc));
}

extern "C" void kernel_launch(void* const* d_in, const int* in_sizes, int n_in,
                              void* d_out, int out_size, void* d_ws, size_t ws_size,
                              hipStream_t stream){
  const float* x  = (const float*)d_in[0];
  const int*   ei = (const int*)d_in[1];
  const float* W0 = (const float*)d_in[2];
  const float* b0 = (const float*)d_in[3];
  const float* W1 = (const float*)d_in[4];
  const float* b1 = (const float*)d_in[5];
  const float* W2 = (const float*)d_in[6];
  const float* b2 = (const float*)d_in[7];
  const float* Wo = (const float*)d_in[8];
  const float* bo = (const float*)d_in[9];
  int n = in_sizes[0];
  int e = in_sizes[1]/2;
  const int* src = ei;
  const int* dst = ei + e;
  float* y = (float*)d_out;

  char* p = (char*)d_ws;
  auto alloc = [&](size_t bytes)->void*{ void* r=p; p += (bytes+255)&~(size_t)255; return r; };
  int*    cnt  = (int*)   alloc((size_t)n*4);
  int*    off  = (int*)   alloc((size_t)n*4);
  int*    cur  = (int*)   alloc((size_t)n*4);
  int*    bsum = (int*)   alloc(512*4);
  int*    bpre = (int*)   alloc(512*4);
  float*  dis  = (float*) alloc((size_t)n*4);
  float*  sb   = (float*) alloc((size_t)n*4);
  float*  zb   = (float*) alloc((size_t)n*4);
  ushort* Wt1  = (ushort*)alloc((size_t)HDIM*HDIM*2);
  ushort* Wt2  = (ushort*)alloc((size_t)HDIM*HDIM*2);
  int2*   cw   = (int2*)  alloc((size_t)e*8);
  uint*   hb0  = (uint*)  alloc((size_t)n*64*4);   // bf16 tables, n x 128 ch
  uint*   hb1  = (uint*)  alloc((size_t)n*64*4);
  uint*   gbuf = (uint*)  alloc((size_t)n*64*4);   // bf16 aggregated features

  int nb = (n+255)/256;
  int eb = (e+255)/256;
  int mb = (n+63)/64;

  k_zero   <<<nb,256,0,stream>>>(cnt,n);
  k_count  <<<eb,256,0,stream>>>(dst,cnt,e);
  k_dis    <<<nb,256,0,stream>>>(cnt,dis,n);
  k_scan1  <<<nb,256,0,stream>>>(cnt,off,bsum,n);
  k_scan2  <<<1,512,0,stream>>>(bsum,bpre,nb);
  k_scan3  <<<nb,256,0,stream>>>(off,cur,bpre,n);
  k_scatter<<<eb,256,0,stream>>>(src,dst,dis,cur,cw,e);
  k_wt     <<<64,256,0,stream>>>(W1,Wt1);
  k_wt     <<<64,256,0,stream>>>(W2,Wt2);

  k_sagg <<<nb,256,0,stream>>>(x,off,cnt,cw,dis,sb,n);
  k_h0   <<<(n*32+255)/256,256,0,stream>>>(sb,W0,b0,hb0,n);

  k_wagg <<<(n+3)/4,256,0,stream>>>(hb0,off,cnt,cw,dis,gbuf,n);
  k_mm   <<<mb,256,0,stream>>>(gbuf,Wt1,b1,(ushort*)hb1,n);

  k_wagg <<<(n+3)/4,256,0,stream>>>(hb1,off,cnt,cw,dis,gbuf,n);
  k_mm   <<<mb,256,0,stream>>>(gbuf,Wt2,b2,(ushort*)hb0,n);

  k_z    <<<(n+3)/4,256,0,stream>>>(hb0,Wo,zb,n);
  k_final<<<nb,256,0,stream>>>(zb,off,cnt,cw,dis,bo,y,n);
}